// Round 18
// baseline (43.672 us; speedup 1.0000x reference)
//
#include <hip/hip_runtime.h>
#include <math.h>

// DTM layer: B=32, N=1024, D=2, M0=0.05, R=2
// out = sqrt( (A_strict(t*) + t*(wb - S_strict(t*)))/wb ), t* = weighted
// 5%-quantile of d2, wb = 0.05*sum_b(w).
// R16 = R15 with 256 SIXTEENTH-OCTAVE buckets (width ratio 1.044) instead of
// 64 quarter-octave: initial bracket 4x tighter -> ONE interpolative refine
// reaches R15's final width (was 2) -> one fewer scan pass + dependent
// DPP round-trip. Bucket pick = 2-level scan (4 buckets/lane). Epilogue and
// concave-envelope estimate unchanged from R15 (passed, absmax 0.0078):
// A-only two-sided pass; S at endpoints exact from histogram CDF / probes.

constexpr int      PER_LANE   = 16;        // 1024 / 64
constexpr float    M0_        = 0.05f;
constexpr unsigned BUCKET_LO  = 1904u;     // raw = bits>>19; bucket0 at d2=2^-8
constexpr unsigned BUCKET_HI  = 2159u;     // BUCKET_LO + 255
constexpr float    WSCALE     = 1048576.0f;            // 2^20
constexpr float    WINV       = 9.5367431640625e-07f;  // 2^-20

template<int CTRL, int RM>
__device__ __forceinline__ unsigned dpp_uadd(unsigned v) {
    unsigned m = (unsigned)__builtin_amdgcn_update_dpp(0, (int)v, CTRL, RM, 0xF, true);
    return v + m;
}
template<int CTRL, int RM>
__device__ __forceinline__ float dpp_fadd(float v) {
    int m = __builtin_amdgcn_update_dpp(0, __float_as_int(v), CTRL, RM, 0xF, true);
    return v + __int_as_float(m);
}
__device__ __forceinline__ float lane63f(float v) {
    return __uint_as_float((unsigned)__builtin_amdgcn_readlane(__float_as_int(v), 63));
}

// u32 inclusive prefix scan across 64 lanes
__device__ __forceinline__ unsigned wave_scan_u32(unsigned v) {
    v = dpp_uadd<0x111,0xF>(v);    // row_shr:1
    v = dpp_uadd<0x112,0xF>(v);    // row_shr:2
    v = dpp_uadd<0x114,0xF>(v);    // row_shr:4
    v = dpp_uadd<0x118,0xF>(v);    // row_shr:8
    v = dpp_uadd<0x142,0xA>(v);    // row_bcast:15
    v = dpp_uadd<0x143,0xC>(v);    // row_bcast:31
    return v;                      // lane63 = total
}
__device__ __forceinline__ float wave_sum1(float v) {
    v = dpp_fadd<0x111,0xF>(v); v = dpp_fadd<0x112,0xF>(v);
    v = dpp_fadd<0x114,0xF>(v); v = dpp_fadd<0x118,0xF>(v);
    v = dpp_fadd<0x142,0xA>(v); v = dpp_fadd<0x143,0xC>(v);
    return lane63f(v);
}
__device__ __forceinline__ void wave_sum2_u(float& a, float& b) {
    a = dpp_fadd<0x111,0xF>(a); b = dpp_fadd<0x111,0xF>(b);
    a = dpp_fadd<0x112,0xF>(a); b = dpp_fadd<0x112,0xF>(b);
    a = dpp_fadd<0x114,0xF>(a); b = dpp_fadd<0x114,0xF>(b);
    a = dpp_fadd<0x118,0xF>(a); b = dpp_fadd<0x118,0xF>(b);
    a = dpp_fadd<0x142,0xA>(a); b = dpp_fadd<0x142,0xA>(b);
    a = dpp_fadd<0x143,0xC>(a); b = dpp_fadd<0x143,0xC>(b);
    a = lane63f(a); b = lane63f(b);
}
__device__ __forceinline__ unsigned rl_u(unsigned v, int l) {
    return (unsigned)__builtin_amdgcn_readlane((int)v, l);
}

__global__ __launch_bounds__(256) void dtm_kernel(
    const float* __restrict__ input,   // [B, N, 2]
    const float* __restrict__ weight,  // [B, N]
    const float* __restrict__ grid,    // [N, 2]
    float* __restrict__ out)           // [B, N]
{
    __shared__ unsigned hist[4][256];  // per-wave private rows -> no barriers
    const int wave = threadIdx.x >> 6;
    const int lane = threadIdx.x & 63;
    const int q    = (blockIdx.x << 2) + wave;
    const int b    = q >> 10;

    const float2 xq = reinterpret_cast<const float2*>(input)[q];

    unsigned* hrow = hist[wave];
    // zero own row (wave-private; DS ops within a wave are ordered)
    #pragma unroll
    for (int z = 0; z < 4; ++z) hrow[lane + 64 * z] = 0u;

    const int base = lane * PER_LANE;
    const float4* w4 = reinterpret_cast<const float4*>(weight + (b << 10) + base);
    const float4* g4 = reinterpret_cast<const float4*>(grid + 2 * base);

    float w[PER_LANE], d2[PER_LANE];
    #pragma unroll
    for (int i = 0; i < 4; ++i) {
        const float4 x = w4[i];
        w[4*i+0] = x.x; w[4*i+1] = x.y; w[4*i+2] = x.z; w[4*i+3] = x.w;
    }

    // ---- pass0: d2 + fixed-point histogram (bucket = 1/16 octave of d2)
    #pragma unroll
    for (int i = 0; i < 8; ++i) {                   // 2 grid points per float4
        const float4 g = g4[i];
        #pragma unroll
        for (int j = 0; j < 2; ++j) {
            const int k  = 2*i + j;
            const float gx = j ? g.z : g.x;
            const float gy = j ? g.w : g.y;
            const float dx = xq.x - gx, dy = xq.y - gy;
            const float dk = dx * dx + dy * dy;
            d2[k] = dk;
            const unsigned raw = __float_as_uint(dk) >> 19;
            const unsigned ibr = min(max(raw, BUCKET_LO), BUCKET_HI);
            const unsigned wi  = (unsigned)(w[k] * WSCALE);
            atomicAdd(&hrow[ibr - BUCKET_LO], wi);  // native ds_add_u32
        }
    }

    // ---- bucket selection: 2-level scan (4 buckets/lane) + ballot (RT 1)
    const unsigned h0 = hrow[4*lane+0], h1 = hrow[4*lane+1];
    const unsigned h2 = hrow[4*lane+2], h3 = hrow[4*lane+3];
    const unsigned s01  = h0 + h1;
    const unsigned s012 = s01 + h2;
    const unsigned hp   = s012 + h3;
    const unsigned cum  = wave_scan_u32(hp);        // CDF through bucket 4*lane+3
    const unsigned totI = rl_u(cum, 63);
    const float    totF = (float)totI;
    const float    wb   = M0_ * totF * WINV;        // float weight bound
    const unsigned wbI  = (unsigned)(M0_ * totF);   // fixed-point bound

    const unsigned long long m = __ballot(cum >= wbI);
    const int p = (int)__ffsll(m) - 1;              // lane whose group crosses wb

    const unsigned cumP  = rl_u(cum,  p);           // CDF through 4p+3
    const unsigned hpP   = rl_u(hp,   p);
    const unsigned s01P  = rl_u(s01,  p);
    const unsigned s012P = rl_u(s012, p);
    const unsigned h0P   = rl_u(h0,   p);
    const unsigned h1P   = rl_u(h1,   p);
    const unsigned h2P   = rl_u(h2,   p);
    const unsigned cbase = cumP - hpP;              // CDF before bucket 4p

    // first bucket j in group with CDF >= wbI
    const unsigned c0 = cbase + h0P;
    const unsigned c1 = cbase + s01P;
    const unsigned c2 = cbase + s012P;
    int j; unsigned cumS, hS;
    if      (c0 >= wbI) { j = 4*p;   cumS = c0;   hS = h0P; }
    else if (c1 >= wbI) { j = 4*p+1; cumS = c1;   hS = h1P; }
    else if (c2 >= wbI) { j = 4*p+2; cumS = c2;   hS = h2P; }
    else                { j = 4*p+3; cumS = cumP; hS = rl_u(h3, p); }

    // bucket edges; histogram CDF at an edge IS the strict sum there
    float lo  = (j == 0) ? 0.f : __uint_as_float(((unsigned)j + BUCKET_LO) << 19);
    float hi  = __uint_as_float(((unsigned)j + 1u + BUCKET_LO) << 19);
    float Wlo = (float)(cumS - hS) * WINV;          // == 0 naturally if j==0
    float Whi = (float)cumS * WINV;

    // ---- 1 interpolative S-only refine (RT 2); bracket 0.044t -> ~0.01t
    {
        float fr = (wb - Wlo) / (Whi - Wlo);
        fr = fminf(fmaxf(fr, 0.06f), 0.94f);
        const float t = lo + (hi - lo) * fr;
        float sv = 0.f;
        #pragma unroll
        for (int k = 0; k < PER_LANE; ++k)
            sv += (d2[k] <= t) ? w[k] : 0.f;
        const float sw = wave_sum1(sv);
        if (sw >= wb) { hi = t; Whi = sw; }
        else          { lo = t; Wlo = sw; }
    }

    // ---- A-only epilogue: strict A at lo and hi (RT 3).
    // S at both ends = Wlo/Whi (strict at edges; probes differ from strict
    // only on exact fp ties -> measure zero).
    float Al = 0.f, Ah = 0.f;
    #pragma unroll
    for (int k = 0; k < PER_LANE; ++k) {
        const float dk = d2[k];
        const float dw = dk * w[k];
        Ah += (dk < hi) ? dw : 0.f;
        Al += (dk < lo) ? dw : 0.f;
    }
    wave_sum2_u(Al, Ah);

    // concave-envelope estimate (val(t) concave piecewise-linear, max at t*;
    // tangent intersection exact when <=1 point inside the bracket)
    const float dS = Whi - Wlo;                      // > 0 (Whi >= wb > Wlo)
    float that = (Ah - Al) / dS;
    that = fminf(fmaxf(that, lo), hi);
    const float vL   = Al + that * (wb - Wlo);       // tangent from lo
    const float vH   = Ah + that * (wb - Whi);       // tangent from hi
    const float vhat = fminf(vL, vH);                // upper bound on wb*val
    const float vmax = fmaxf(Al + lo * (wb - Wlo),
                             Ah + hi * (wb - Whi));  // lower bound
    const float val  = 0.5f * (vhat + vmax) / wb;

    if (lane == 0) out[q] = sqrtf(fmaxf(val, 0.f));
}

extern "C" void kernel_launch(void* const* d_in, const int* in_sizes, int n_in,
                              void* d_out, int out_size, void* d_ws, size_t ws_size,
                              hipStream_t stream) {
    const float* input  = (const float*)d_in[0];   // [32,1024,2]
    const float* weight = (const float*)d_in[1];   // [32,1024]
    const float* grid   = (const float*)d_in[2];   // [1024,2]
    float* out = (float*)d_out;                    // [32,1024]

    const int total_q = 32 * 1024;                 // B*N
    dim3 blk(256);                                 // 4 waves/block, 1 query/wave
    dim3 grd(total_q / 4);                         // 8192 blocks
    hipLaunchKernelGGL(dtm_kernel, grd, blk, 0, stream,
                       input, weight, grid, out);
}